// Round 2
// baseline (446.368 us; speedup 1.0000x reference)
//
#include <hip/hip_runtime.h>
#include <hip/hip_bf16.h>
#include <stdint.h>

#define Bb 4
#define Nn 2048
#define Dd 1024
#define Hh 16
#define DHd 64
#define Mm (Bb*Nn)     /* 8192 */
#define D3 (3*Dd)      /* 3072 */

typedef unsigned short u16;
typedef __attribute__((ext_vector_type(8))) short bf16x8;
typedef __attribute__((ext_vector_type(4))) float f32x4;
typedef __attribute__((ext_vector_type(4))) unsigned int u32x4;

__device__ __forceinline__ u16 f2bf(float f) {
    unsigned int u = __float_as_uint(f);
    u = (u + 0x7FFFu + ((u >> 16) & 1u)) >> 16;
    return (u16)u;
}

#define GLOAD16(g, l)                                                          \
    __builtin_amdgcn_global_load_lds(                                          \
        (const __attribute__((address_space(1))) unsigned int*)(g),            \
        (__attribute__((address_space(3))) unsigned int*)(l), 16, 0, 0)

// ---------------- fp32 -> bf16 convert ----------------
__global__ void cvt_f32_bf16(const float* __restrict__ in, u16* __restrict__ out, int n4) {
    int i = blockIdx.x * blockDim.x + threadIdx.x;
    int stride = gridDim.x * blockDim.x;
    for (; i < n4; i += stride) {
        float4 v = ((const float4*)in)[i];
        u16 o0 = f2bf(v.x), o1 = f2bf(v.y), o2 = f2bf(v.z), o3 = f2bf(v.w);
        unsigned int lo = (unsigned int)o0 | ((unsigned int)o1 << 16);
        unsigned int hi = (unsigned int)o2 | ((unsigned int)o3 << 16);
        ((uint2*)out)[i] = make_uint2(lo, hi);
    }
}

// ---------------- bf16 GEMM: C[M][N] = A[M][K] * B[N][K]^T ----------------
// m97 structure: 128x128 tile, BK=32, 256 threads (4 waves 2x2), global_load_lds(16B)
template<int OUT_F32>
__global__ __launch_bounds__(256) void gemm_bt(const u16* __restrict__ A,
                                               const u16* __restrict__ Bm,
                                               void* __restrict__ C,
                                               int M, int Nout, int K) {
    __shared__ u16 As[128 * 32];
    __shared__ u16 Bs[128 * 32];
    const int t = threadIdx.x;
    const int lane = t & 63;
    const int w = t >> 6;
    const int wr = w >> 1, wc = w & 1;
    const int l15 = lane & 15, l4 = lane >> 4;
    const int m0 = blockIdx.y * 128;
    const int n0 = blockIdx.x * 128;

    f32x4 acc[4][4] = {};

    const int srow = t >> 2;          // 0..63
    const int scol = (t & 3) * 8;     // k element offset

    const u16* Ag0 = A + (size_t)(m0 + srow) * K + scol;
    const u16* Ag1 = A + (size_t)(m0 + 64 + srow) * K + scol;
    const u16* Bg0 = Bm + (size_t)(n0 + srow) * K + scol;
    const u16* Bg1 = Bm + (size_t)(n0 + 64 + srow) * K + scol;

    for (int k0 = 0; k0 < K; k0 += 32) {
        __syncthreads();
        GLOAD16(Ag0 + k0, &As[t * 8]);
        GLOAD16(Ag1 + k0, &As[2048 + t * 8]);
        GLOAD16(Bg0 + k0, &Bs[t * 8]);
        GLOAD16(Bg1 + k0, &Bs[2048 + t * 8]);
        __syncthreads();

        bf16x8 a[4], b[4];
#pragma unroll
        for (int mi = 0; mi < 4; mi++)
            a[mi] = *(const bf16x8*)&As[(wr * 64 + mi * 16 + l15) * 32 + l4 * 8];
#pragma unroll
        for (int nj = 0; nj < 4; nj++)
            b[nj] = *(const bf16x8*)&Bs[(wc * 64 + nj * 16 + l15) * 32 + l4 * 8];
#pragma unroll
        for (int mi = 0; mi < 4; mi++)
#pragma unroll
            for (int nj = 0; nj < 4; nj++)
                acc[mi][nj] = __builtin_amdgcn_mfma_f32_16x16x32_bf16(a[mi], b[nj], acc[mi][nj], 0, 0, 0);
    }

#pragma unroll
    for (int mi = 0; mi < 4; mi++) {
#pragma unroll
        for (int nj = 0; nj < 4; nj++) {
            int col = n0 + wc * 64 + nj * 16 + l15;
#pragma unroll
            for (int r = 0; r < 4; r++) {
                int row = m0 + wr * 64 + mi * 16 + l4 * 4 + r;
                float v = acc[mi][nj][r];
                if (OUT_F32)
                    ((float*)C)[(size_t)row * Nout + col] = v;
                else
                    ((u16*)C)[(size_t)row * Nout + col] = f2bf(v);
            }
        }
    }
}

// ---------------- causal flash attention ----------------
// grid: (N/64, B*H). 256 threads = 4 waves; wave w owns q-rows [q0+16w, q0+16w+16)
__global__ __launch_bounds__(256) void attn(const u16* __restrict__ qkv, u16* __restrict__ y) {
    __shared__ u16 Kt[64 * 64];        // [krow][d]
    __shared__ u16 Vt[64 * 64];        // [d][krow]
    __shared__ u16 Pb[4][16 * 64];     // per-wave P [qrow][k]

    const int t = threadIdx.x;
    const int lane = t & 63;
    const int w = t >> 6;
    const int l15 = lane & 15, l4 = lane >> 4;
    const int qt = blockIdx.x;
    const int bh = blockIdx.y;
    const int b = bh >> 4, h = bh & 15;
    const int q0 = qt * 64;

    const u16* qbase = qkv + (size_t)(b * Nn) * D3 + h * DHd;

    // Q fragments for this wave (rows q0 + w*16 + l15)
    bf16x8 qf[2];
    {
        const u16* qrow = qbase + (size_t)(q0 + w * 16 + l15) * D3;
        qf[0] = *(const bf16x8*)(qrow + l4 * 8);
        qf[1] = *(const bf16x8*)(qrow + 32 + l4 * 8);
    }

    f32x4 o[4] = {};
    float m_[4] = {-1e30f, -1e30f, -1e30f, -1e30f};
    float l_[4] = {0.f, 0.f, 0.f, 0.f};

    const int srow = t >> 2;          // 0..63
    const int sd = (t & 3) * 16;      // 0,16,32,48

    for (int kt = 0; kt <= qt; ++kt) {
        const int k0 = kt * 64;
        __syncthreads();
        {   // stage K rows and V^T
            const u16* krow = qbase + Dd + (size_t)(k0 + srow) * D3 + sd;
            u32x4 k0v = *(const u32x4*)(krow);
            u32x4 k1v = *(const u32x4*)(krow + 8);
            *(u32x4*)&Kt[srow * 64 + sd] = k0v;
            *(u32x4*)&Kt[srow * 64 + sd + 8] = k1v;
            const u16* vrow = qbase + 2 * Dd + (size_t)(k0 + srow) * D3 + sd;
            u32x4 v0 = *(const u32x4*)(vrow);
            u32x4 v1 = *(const u32x4*)(vrow + 8);
            u16 vv[16];
            *(u32x4*)&vv[0] = v0;
            *(u32x4*)&vv[8] = v1;
#pragma unroll
            for (int j = 0; j < 16; j++) Vt[(sd + j) * 64 + srow] = vv[j];
        }
        __syncthreads();

        const int diag = (kt == qt);

        // ---- compute all four 16-col S slices for this 64-wide K tile ----
        f32x4 sv[4];
#pragma unroll
        for (int kc = 0; kc < 4; ++kc) {
            f32x4 s = {};
            bf16x8 kf0 = *(const bf16x8*)&Kt[(kc * 16 + l15) * 64 + l4 * 8];
            bf16x8 kf1 = *(const bf16x8*)&Kt[(kc * 16 + l15) * 64 + 32 + l4 * 8];
            s = __builtin_amdgcn_mfma_f32_16x16x32_bf16(qf[0], kf0, s, 0, 0, 0);
            s = __builtin_amdgcn_mfma_f32_16x16x32_bf16(qf[1], kf1, s, 0, 0, 0);
#pragma unroll
            for (int r = 0; r < 4; r++) {
                float x = s[r] * 0.125f;
                if (diag) {
                    int kg = k0 + kc * 16 + l15;
                    int qg = q0 + w * 16 + l4 * 4 + r;
                    if (kg > qg) x = -1e30f;
                }
                sv[kc][r] = x;
            }
        }

        // ---- ONE online-softmax update per q-row over the whole 64 cols ----
#pragma unroll
        for (int r = 0; r < 4; r++) {
            float v = fmaxf(fmaxf(sv[0][r], sv[1][r]), fmaxf(sv[2][r], sv[3][r]));
            v = fmaxf(v, __shfl_xor(v, 1));
            v = fmaxf(v, __shfl_xor(v, 2));
            v = fmaxf(v, __shfl_xor(v, 4));
            v = fmaxf(v, __shfl_xor(v, 8));
            float newm = fmaxf(m_[r], v);
            float corr = __expf(m_[r] - newm);
            float ps = 0.f;
#pragma unroll
            for (int kc = 0; kc < 4; ++kc) {
                float p = __expf(sv[kc][r] - newm);
                ps += p;
                Pb[w][(l4 * 4 + r) * 64 + kc * 16 + l15] = f2bf(p);
            }
            ps += __shfl_xor(ps, 1);
            ps += __shfl_xor(ps, 2);
            ps += __shfl_xor(ps, 4);
            ps += __shfl_xor(ps, 8);
            l_[r] = l_[r] * corr + ps;
            m_[r] = newm;
#pragma unroll
            for (int db = 0; db < 4; db++) o[db][r] *= corr;
        }

        // ---- P * V ----
#pragma unroll
        for (int kg = 0; kg < 2; kg++) {
            bf16x8 pa = *(const bf16x8*)&Pb[w][l15 * 64 + kg * 32 + l4 * 8];
#pragma unroll
            for (int db = 0; db < 4; db++) {
                bf16x8 vb = *(const bf16x8*)&Vt[(db * 16 + l15) * 64 + kg * 32 + l4 * 8];
                o[db] = __builtin_amdgcn_mfma_f32_16x16x32_bf16(pa, vb, o[db], 0, 0, 0);
            }
        }
    }

#pragma unroll
    for (int r = 0; r < 4; r++) {
        float rcp = 1.f / l_[r];
        int qg = q0 + w * 16 + l4 * 4 + r;
        u16* yrow = y + (size_t)(b * Nn + qg) * Dd + h * DHd;
#pragma unroll
        for (int db = 0; db < 4; db++)
            yrow[db * 16 + l15] = f2bf(o[db][r] * rcp);
    }
}

extern "C" void kernel_launch(void* const* d_in, const int* in_sizes, int n_in,
                              void* d_out, int out_size, void* d_ws, size_t ws_size,
                              hipStream_t stream) {
    const float* x = (const float*)d_in[0];
    const float* Wqkv = (const float*)d_in[1];
    const float* Wout = (const float*)d_in[2];

    char* ws = (char*)d_ws;
    size_t off = 0;
    u16* xb = (u16*)(ws + off);    off += (size_t)Mm * Dd * 2;     // 16 MiB
    u16* wqkvb = (u16*)(ws + off); off += (size_t)D3 * Dd * 2;     //  6 MiB
    u16* woutb = (u16*)(ws + off); off += (size_t)Dd * Dd * 2;     //  2 MiB
    u16* qkv = (u16*)(ws + off);   off += (size_t)Mm * D3 * 2;     // 48 MiB
    u16* yb = (u16*)(ws + off);    off += (size_t)Mm * Dd * 2;     // 16 MiB

    cvt_f32_bf16<<<4096, 256, 0, stream>>>(x, xb, Mm * Dd / 4);
    cvt_f32_bf16<<<1024, 256, 0, stream>>>(Wqkv, wqkvb, D3 * Dd / 4);
    cvt_f32_bf16<<<512, 256, 0, stream>>>(Wout, woutb, Dd * Dd / 4);

    gemm_bt<0><<<dim3(D3 / 128, Mm / 128), 256, 0, stream>>>(xb, wqkvb, qkv, Mm, D3, Dd);
    attn<<<dim3(Nn / 64, Bb * Hh), 256, 0, stream>>>(qkv, yb);
    gemm_bt<1><<<dim3(Dd / 128, Mm / 128), 256, 0, stream>>>(yb, woutb, d_out, Mm, Dd, Dd);
}

// Round 3
// 352.225 us; speedup vs baseline: 1.2673x; 1.2673x over previous
//
#include <hip/hip_runtime.h>
#include <hip/hip_bf16.h>
#include <stdint.h>

#define Bb 4
#define Nn 2048
#define Dd 1024
#define Hh 16
#define DHd 64
#define Mm (Bb*Nn)     /* 8192 */
#define D3 (3*Dd)      /* 3072 */

typedef unsigned short u16;
typedef __attribute__((ext_vector_type(8))) short bf16x8;
typedef __attribute__((ext_vector_type(4))) float f32x4;
typedef __attribute__((ext_vector_type(4))) unsigned int u32x4;

__device__ __forceinline__ u16 f2bf(float f) {
    unsigned int u = __float_as_uint(f);
    u = (u + 0x7FFFu + ((u >> 16) & 1u)) >> 16;
    return (u16)u;
}

#define GLOAD16(g, l)                                                          \
    __builtin_amdgcn_global_load_lds(                                          \
        (const __attribute__((address_space(1))) unsigned int*)(g),            \
        (__attribute__((address_space(3))) unsigned int*)(l), 16, 0, 0)

// ---------------- fp32 -> bf16 convert ----------------
__global__ void cvt_f32_bf16(const float* __restrict__ in, u16* __restrict__ out, int n4) {
    int i = blockIdx.x * blockDim.x + threadIdx.x;
    int stride = gridDim.x * blockDim.x;
    for (; i < n4; i += stride) {
        float4 v = ((const float4*)in)[i];
        u16 o0 = f2bf(v.x), o1 = f2bf(v.y), o2 = f2bf(v.z), o3 = f2bf(v.w);
        unsigned int lo = (unsigned int)o0 | ((unsigned int)o1 << 16);
        unsigned int hi = (unsigned int)o2 | ((unsigned int)o3 << 16);
        ((uint2*)out)[i] = make_uint2(lo, hi);
    }
}

// ---------------- bf16 GEMM: C[M][N] = A[M][K] * B[N][K]^T ----------------
template<int OUT_F32>
__global__ __launch_bounds__(256) void gemm_bt(const u16* __restrict__ A,
                                               const u16* __restrict__ Bm,
                                               void* __restrict__ C,
                                               int M, int Nout, int K) {
    __shared__ u16 As[128 * 32];
    __shared__ u16 Bs[128 * 32];
    const int t = threadIdx.x;
    const int lane = t & 63;
    const int w = t >> 6;
    const int wr = w >> 1, wc = w & 1;
    const int l15 = lane & 15, l4 = lane >> 4;
    const int m0 = blockIdx.y * 128;
    const int n0 = blockIdx.x * 128;

    f32x4 acc[4][4] = {};

    const int srow = t >> 2;          // 0..63
    const int scol = (t & 3) * 8;     // k element offset

    const u16* Ag0 = A + (size_t)(m0 + srow) * K + scol;
    const u16* Ag1 = A + (size_t)(m0 + 64 + srow) * K + scol;
    const u16* Bg0 = Bm + (size_t)(n0 + srow) * K + scol;
    const u16* Bg1 = Bm + (size_t)(n0 + 64 + srow) * K + scol;

    for (int k0 = 0; k0 < K; k0 += 32) {
        __syncthreads();
        GLOAD16(Ag0 + k0, &As[t * 8]);
        GLOAD16(Ag1 + k0, &As[2048 + t * 8]);
        GLOAD16(Bg0 + k0, &Bs[t * 8]);
        GLOAD16(Bg1 + k0, &Bs[2048 + t * 8]);
        __syncthreads();

        bf16x8 a[4], b[4];
#pragma unroll
        for (int mi = 0; mi < 4; mi++)
            a[mi] = *(const bf16x8*)&As[(wr * 64 + mi * 16 + l15) * 32 + l4 * 8];
#pragma unroll
        for (int nj = 0; nj < 4; nj++)
            b[nj] = *(const bf16x8*)&Bs[(wc * 64 + nj * 16 + l15) * 32 + l4 * 8];
#pragma unroll
        for (int mi = 0; mi < 4; mi++)
#pragma unroll
            for (int nj = 0; nj < 4; nj++)
                acc[mi][nj] = __builtin_amdgcn_mfma_f32_16x16x32_bf16(a[mi], b[nj], acc[mi][nj], 0, 0, 0);
    }

#pragma unroll
    for (int mi = 0; mi < 4; mi++) {
#pragma unroll
        for (int nj = 0; nj < 4; nj++) {
            int col = n0 + wc * 64 + nj * 16 + l15;
#pragma unroll
            for (int r = 0; r < 4; r++) {
                int row = m0 + wr * 64 + mi * 16 + l4 * 4 + r;
                float v = acc[mi][nj][r];
                if (OUT_F32)
                    ((float*)C)[(size_t)row * Nout + col] = v;
                else
                    ((u16*)C)[(size_t)row * Nout + col] = f2bf(v);
            }
        }
    }
}

// ---------------- causal flash attention ----------------
// grid: (N/64, B*H). 256 threads = 4 waves; wave w owns q-rows [q0+16w, q0+16w+16)
// All LDS tiles XOR-swizzled at 16B-chunk granularity: chunk_phys = chunk ^ (row&7)
__global__ __launch_bounds__(256) void attn(const u16* __restrict__ qkv, u16* __restrict__ y) {
    __shared__ u16 Kt[64 * 64];        // [krow][d]   swizzled
    __shared__ u16 Vt[64 * 64];        // [d][krow]   swizzled
    __shared__ u16 Pb[4][16 * 64];     // per-wave P [qrow][k]  swizzled

    const int t = threadIdx.x;
    const int lane = t & 63;
    const int w = t >> 6;
    const int l15 = lane & 15, l4 = lane >> 4;
    const int qt = gridDim.x - 1 - blockIdx.x;   // long blocks first
    const int bh = blockIdx.y;
    const int b = bh >> 4, h = bh & 15;
    const int q0 = qt * 64;

    const u16* qbase = qkv + (size_t)(b * Nn) * D3 + h * DHd;

    // Q fragments for this wave (rows q0 + w*16 + l15)
    bf16x8 qf[2];
    {
        const u16* qrow = qbase + (size_t)(q0 + w * 16 + l15) * D3;
        qf[0] = *(const bf16x8*)(qrow + l4 * 8);
        qf[1] = *(const bf16x8*)(qrow + 32 + l4 * 8);
    }

    f32x4 o[4] = {};
    float m_[4] = {-1e30f, -1e30f, -1e30f, -1e30f};
    float l_[4] = {0.f, 0.f, 0.f, 0.f};

    // V staging mapping: thread handles krow pair (2i, 2i+1), dims sd..sd+7
    const int vi = t & 31;             // row pair index 0..31
    const int vsd = (t >> 5) * 8;      // dim group 0..56

    for (int kt = 0; kt <= qt; ++kt) {
        const int k0 = kt * 64;
        __syncthreads();

        // ---- K: global_load_lds with pre-swizzled global source ----
#pragma unroll
        for (int p = 0; p < 2; ++p) {
            int chunk = p * 256 + t;           // 512 16B-chunks total
            int row = chunk >> 3;
            int ccol = chunk & 7;
            const u16* src = qbase + Dd + (size_t)(k0 + row) * D3 + ((ccol ^ (row & 7)) << 3);
            GLOAD16(src, &Kt[chunk * 8]);
        }

        // ---- V: reg-staged transpose, paired-column u32 writes, swizzled ----
        {
            const u16* vr0 = qbase + 2 * Dd + (size_t)(k0 + 2 * vi) * D3 + vsd;
            const u16* vr1 = vr0 + D3;
            u32x4 va = *(const u32x4*)vr0;
            u32x4 vb_ = *(const u32x4*)vr1;
            u16 av[8], bv[8];
            *(u32x4*)av = va;
            *(u32x4*)bv = vb_;
#pragma unroll
            for (int j = 0; j < 8; j++) {
                int d = vsd + j;
                unsigned int word = (unsigned int)av[j] | ((unsigned int)bv[j] << 16);
                int idx = d * 64 + ((((2 * vi) >> 3) ^ (d & 7)) << 3) + ((2 * vi) & 7);
                *(unsigned int*)&Vt[idx] = word;
            }
        }
        __syncthreads();

        const int diag = (kt == qt);

        // ---- QK^T: four 16-col S slices ----
        f32x4 sv[4];
#pragma unroll
        for (int kc = 0; kc < 4; ++kc) {
            f32x4 s = {};
            int row = kc * 16 + l15;
            int sw = (row & 7);
            bf16x8 kf0 = *(const bf16x8*)&Kt[row * 64 + ((l4 ^ sw) << 3)];
            bf16x8 kf1 = *(const bf16x8*)&Kt[row * 64 + (((4 + l4) ^ sw) << 3)];
            s = __builtin_amdgcn_mfma_f32_16x16x32_bf16(qf[0], kf0, s, 0, 0, 0);
            s = __builtin_amdgcn_mfma_f32_16x16x32_bf16(qf[1], kf1, s, 0, 0, 0);
#pragma unroll
            for (int r = 0; r < 4; r++) {
                float x = s[r] * 0.125f;
                if (diag) {
                    int kg = k0 + kc * 16 + l15;
                    int qg = q0 + w * 16 + l4 * 4 + r;
                    if (kg > qg) x = -1e30f;
                }
                sv[kc][r] = x;
            }
        }

        // ---- online softmax: one update per q-row over 64 cols ----
#pragma unroll
        for (int r = 0; r < 4; r++) {
            float v = fmaxf(fmaxf(sv[0][r], sv[1][r]), fmaxf(sv[2][r], sv[3][r]));
            v = fmaxf(v, __shfl_xor(v, 1));
            v = fmaxf(v, __shfl_xor(v, 2));
            v = fmaxf(v, __shfl_xor(v, 4));
            v = fmaxf(v, __shfl_xor(v, 8));
            float newm = fmaxf(m_[r], v);
            float corr = __expf(m_[r] - newm);
            float ps = 0.f;
            int q = l4 * 4 + r;
#pragma unroll
            for (int kc = 0; kc < 4; ++kc) {
                float p = __expf(sv[kc][r] - newm);
                ps += p;
                int chunk = kc * 2 + (l15 >> 3);
                int idx = q * 64 + ((chunk ^ (q & 7)) << 3) + (l15 & 7);
                Pb[w][idx] = f2bf(p);
            }
            ps += __shfl_xor(ps, 1);
            ps += __shfl_xor(ps, 2);
            ps += __shfl_xor(ps, 4);
            ps += __shfl_xor(ps, 8);
            l_[r] = l_[r] * corr + ps;
            m_[r] = newm;
#pragma unroll
            for (int db = 0; db < 4; db++) o[db][r] *= corr;
        }

        asm volatile("s_waitcnt lgkmcnt(0)" ::: "memory");

        // ---- P * V ----
#pragma unroll
        for (int kg = 0; kg < 2; kg++) {
            bf16x8 pa = *(const bf16x8*)&Pb[w][l15 * 64 + (((kg * 4 + l4) ^ (l15 & 7)) << 3)];
#pragma unroll
            for (int db = 0; db < 4; db++) {
                int d = db * 16 + l15;
                bf16x8 vb = *(const bf16x8*)&Vt[d * 64 + (((kg * 4 + l4) ^ (d & 7)) << 3)];
                o[db] = __builtin_amdgcn_mfma_f32_16x16x32_bf16(pa, vb, o[db], 0, 0, 0);
            }
        }
    }

#pragma unroll
    for (int r = 0; r < 4; r++) {
        float rcp = 1.f / l_[r];
        int qg = q0 + w * 16 + l4 * 4 + r;
        u16* yrow = y + (size_t)(b * Nn + qg) * Dd + h * DHd;
#pragma unroll
        for (int db = 0; db < 4; db++)
            yrow[db * 16 + l15] = f2bf(o[db][r] * rcp);
    }
}

extern "C" void kernel_launch(void* const* d_in, const int* in_sizes, int n_in,
                              void* d_out, int out_size, void* d_ws, size_t ws_size,
                              hipStream_t stream) {
    const float* x = (const float*)d_in[0];
    const float* Wqkv = (const float*)d_in[1];
    const float* Wout = (const float*)d_in[2];

    char* ws = (char*)d_ws;
    size_t off = 0;
    u16* xb = (u16*)(ws + off);    off += (size_t)Mm * Dd * 2;     // 16 MiB
    u16* wqkvb = (u16*)(ws + off); off += (size_t)D3 * Dd * 2;     //  6 MiB
    u16* woutb = (u16*)(ws + off); off += (size_t)Dd * Dd * 2;     //  2 MiB
    u16* qkv = (u16*)(ws + off);   off += (size_t)Mm * D3 * 2;     // 48 MiB
    u16* yb = (u16*)(ws + off);    off += (size_t)Mm * Dd * 2;     // 16 MiB

    cvt_f32_bf16<<<4096, 256, 0, stream>>>(x, xb, Mm * Dd / 4);
    cvt_f32_bf16<<<1024, 256, 0, stream>>>(Wqkv, wqkvb, D3 * Dd / 4);
    cvt_f32_bf16<<<512, 256, 0, stream>>>(Wout, woutb, Dd * Dd / 4);

    gemm_bt<0><<<dim3(D3 / 128, Mm / 128), 256, 0, stream>>>(xb, wqkvb, qkv, Mm, D3, Dd);
    attn<<<dim3(Nn / 64, Bb * Hh), 256, 0, stream>>>(qkv, yb);
    gemm_bt<1><<<dim3(Dd / 128, Mm / 128), 256, 0, stream>>>(yb, woutb, d_out, Mm, Dd, Dd);
}

// Round 4
// 323.606 us; speedup vs baseline: 1.3794x; 1.0884x over previous
//
#include <hip/hip_runtime.h>
#include <hip/hip_bf16.h>
#include <stdint.h>

#define Bb 4
#define Nn 2048
#define Dd 1024
#define Hh 16
#define DHd 64
#define Mm (Bb*Nn)     /* 8192 */
#define D3 (3*Dd)      /* 3072 */

typedef unsigned short u16;
typedef __attribute__((ext_vector_type(8))) short bf16x8;
typedef __attribute__((ext_vector_type(4))) float f32x4;
typedef __attribute__((ext_vector_type(2))) unsigned int u32x2;
typedef __attribute__((ext_vector_type(4))) unsigned int u32x4;

__device__ __forceinline__ u16 f2bf(float f) {
    unsigned int u = __float_as_uint(f);
    u = (u + 0x7FFFu + ((u >> 16) & 1u)) >> 16;
    return (u16)u;
}

#define GLOAD16(g, l)                                                          \
    __builtin_amdgcn_global_load_lds(                                          \
        (const __attribute__((address_space(1))) unsigned int*)(g),            \
        (__attribute__((address_space(3))) unsigned int*)(l), 16, 0, 0)

// ---------------- fp32 -> bf16 convert ----------------
__global__ void cvt_f32_bf16(const float* __restrict__ in, u16* __restrict__ out, int n4) {
    int i = blockIdx.x * blockDim.x + threadIdx.x;
    int stride = gridDim.x * blockDim.x;
    for (; i < n4; i += stride) {
        float4 v = ((const float4*)in)[i];
        u16 o0 = f2bf(v.x), o1 = f2bf(v.y), o2 = f2bf(v.z), o3 = f2bf(v.w);
        unsigned int lo = (unsigned int)o0 | ((unsigned int)o1 << 16);
        unsigned int hi = (unsigned int)o2 | ((unsigned int)o3 << 16);
        ((uint2*)out)[i] = make_uint2(lo, hi);
    }
}

// ---------------- bf16 GEMM: C[M][N] = A[M][K] * B[N][K]^T ----------------
template<int OUT_F32>
__global__ __launch_bounds__(256) void gemm_bt(const u16* __restrict__ A,
                                               const u16* __restrict__ Bm,
                                               void* __restrict__ C,
                                               int M, int Nout, int K) {
    __shared__ u16 As[128 * 32];
    __shared__ u16 Bs[128 * 32];
    const int t = threadIdx.x;
    const int lane = t & 63;
    const int w = t >> 6;
    const int wr = w >> 1, wc = w & 1;
    const int l15 = lane & 15, l4 = lane >> 4;
    const int m0 = blockIdx.y * 128;
    const int n0 = blockIdx.x * 128;

    f32x4 acc[4][4] = {};

    const int srow = t >> 2;
    const int scol = (t & 3) * 8;

    const u16* Ag0 = A + (size_t)(m0 + srow) * K + scol;
    const u16* Ag1 = A + (size_t)(m0 + 64 + srow) * K + scol;
    const u16* Bg0 = Bm + (size_t)(n0 + srow) * K + scol;
    const u16* Bg1 = Bm + (size_t)(n0 + 64 + srow) * K + scol;

    for (int k0 = 0; k0 < K; k0 += 32) {
        __syncthreads();
        GLOAD16(Ag0 + k0, &As[t * 8]);
        GLOAD16(Ag1 + k0, &As[2048 + t * 8]);
        GLOAD16(Bg0 + k0, &Bs[t * 8]);
        GLOAD16(Bg1 + k0, &Bs[2048 + t * 8]);
        __syncthreads();

        bf16x8 a[4], b[4];
#pragma unroll
        for (int mi = 0; mi < 4; mi++)
            a[mi] = *(const bf16x8*)&As[(wr * 64 + mi * 16 + l15) * 32 + l4 * 8];
#pragma unroll
        for (int nj = 0; nj < 4; nj++)
            b[nj] = *(const bf16x8*)&Bs[(wc * 64 + nj * 16 + l15) * 32 + l4 * 8];
#pragma unroll
        for (int mi = 0; mi < 4; mi++)
#pragma unroll
            for (int nj = 0; nj < 4; nj++)
                acc[mi][nj] = __builtin_amdgcn_mfma_f32_16x16x32_bf16(a[mi], b[nj], acc[mi][nj], 0, 0, 0);
    }

#pragma unroll
    for (int mi = 0; mi < 4; mi++) {
#pragma unroll
        for (int nj = 0; nj < 4; nj++) {
            int col = n0 + wc * 64 + nj * 16 + l15;
#pragma unroll
            for (int r = 0; r < 4; r++) {
                int row = m0 + wr * 64 + mi * 16 + l4 * 4 + r;
                float v = acc[mi][nj][r];
                if (OUT_F32)
                    ((float*)C)[(size_t)row * Nout + col] = v;
                else
                    ((u16*)C)[(size_t)row * Nout + col] = f2bf(v);
            }
        }
    }
}

// ---------------- causal flash attention ----------------
// grid: (N/128, B*H). 512 threads = 8 waves; wave w owns q-rows [q0+16w, q0+16w+16)
// K,V double-buffered; K via global_load_lds w/ pre-swizzled global src;
// V reg-staged transpose. All LDS XOR-swizzled at 16B chunks: chunk ^= (row&7).
__global__ __launch_bounds__(512) void attn(const u16* __restrict__ qkv, u16* __restrict__ y) {
    __shared__ u16 Kt[2][64 * 64];     // [buf][krow][d]  swizzled
    __shared__ u16 Vt[2][64 * 64];     // [buf][d][krow]  swizzled
    __shared__ u16 Pb[8][16 * 64];     // per-wave P [qrow][k]  swizzled

    const int t = threadIdx.x;
    const int lane = t & 63;
    const int w = t >> 6;
    const int l15 = lane & 15, l4 = lane >> 4;
    const int qt = gridDim.x - 1 - blockIdx.x;   // long blocks first
    const int bh = blockIdx.y;
    const int b = bh >> 4, h = bh & 15;
    const int q0 = qt * 128;
    const int ktmax = 2 * qt + 1;

    const u16* qbase = qkv + (size_t)(b * Nn) * D3 + h * DHd;
    const u16* Kg = qbase + Dd;
    const u16* Vg = qbase + 2 * Dd;

    // Q fragments for this wave (rows q0 + w*16 + l15)
    bf16x8 qf[2];
    {
        const u16* qrow = qbase + (size_t)(q0 + w * 16 + l15) * D3;
        qf[0] = *(const bf16x8*)(qrow + l4 * 8);
        qf[1] = *(const bf16x8*)(qrow + 32 + l4 * 8);
    }

    f32x4 o[4] = {};
    float m_[4] = {-1e30f, -1e30f, -1e30f, -1e30f};
    float l_[4] = {0.f, 0.f, 0.f, 0.f};

    // staging maps
    const int krow = t >> 3;            // K: 512 chunks of 16B, row 0..63
    const int kccol = t & 7;
    const int vi = t & 31;              // V: row pair (2vi, 2vi+1)
    const int vsd = (t >> 5) * 4;       // dims vsd..vsd+3

    u32x2 va, vb_;

    // ---- prologue: stage tile 0 into buf 0 ----
    {
        const u16* src = Kg + (size_t)krow * D3 + ((kccol ^ (krow & 7)) << 3);
        GLOAD16(src, &Kt[0][t * 8]);
        const u16* vr0 = Vg + (size_t)(2 * vi) * D3 + vsd;
        va = *(const u32x2*)vr0;
        vb_ = *(const u32x2*)(vr0 + D3);
    }
    asm volatile("s_waitcnt vmcnt(0)" ::: "memory");
    {
        u16 av[4], bv[4];
        *(u32x2*)av = va; *(u32x2*)bv = vb_;
#pragma unroll
        for (int j = 0; j < 4; j++) {
            int d = vsd + j;
            unsigned int word = (unsigned int)av[j] | ((unsigned int)bv[j] << 16);
            int idx = d * 64 + ((((2 * vi) >> 3) ^ (d & 7)) << 3) + ((2 * vi) & 7);
            *(unsigned int*)&Vt[0][idx] = word;
        }
    }
    __syncthreads();

    int cur = 0;
    for (int kt = 0; kt <= ktmax; ++kt) {
        const int k0 = kt * 64;
        const int havenext = (kt < ktmax);

        // ---- issue prefetch of tile kt+1 into buf cur^1 ----
        if (havenext) {
            const int nk0 = k0 + 64;
            const u16* src = Kg + (size_t)(nk0 + krow) * D3 + ((kccol ^ (krow & 7)) << 3);
            GLOAD16(src, &Kt[cur ^ 1][t * 8]);
            const u16* vr0 = Vg + (size_t)(nk0 + 2 * vi) * D3 + vsd;
            va = *(const u32x2*)vr0;
            vb_ = *(const u32x2*)(vr0 + D3);
        }

        const int qwmin = q0 + w * 16;
        const int skip = (k0 > qwmin + 15);

        if (!skip) {
            const int needmask = (k0 + 63 > qwmin);

            // ---- QK^T: four 16-col S slices ----
            f32x4 sv[4];
#pragma unroll
            for (int kc = 0; kc < 4; ++kc) {
                f32x4 s = {};
                int row = kc * 16 + l15;
                int sw = (row & 7);
                bf16x8 kf0 = *(const bf16x8*)&Kt[cur][row * 64 + ((l4 ^ sw) << 3)];
                bf16x8 kf1 = *(const bf16x8*)&Kt[cur][row * 64 + (((4 + l4) ^ sw) << 3)];
                s = __builtin_amdgcn_mfma_f32_16x16x32_bf16(qf[0], kf0, s, 0, 0, 0);
                s = __builtin_amdgcn_mfma_f32_16x16x32_bf16(qf[1], kf1, s, 0, 0, 0);
#pragma unroll
                for (int r = 0; r < 4; r++) {
                    float x = s[r] * 0.125f;
                    if (needmask) {
                        int kg = k0 + kc * 16 + l15;
                        int qg = qwmin + l4 * 4 + r;
                        if (kg > qg) x = -1e30f;
                    }
                    sv[kc][r] = x;
                }
            }

            // ---- online softmax over the 64 cols ----
#pragma unroll
            for (int r = 0; r < 4; r++) {
                float v = fmaxf(fmaxf(sv[0][r], sv[1][r]), fmaxf(sv[2][r], sv[3][r]));
                v = fmaxf(v, __shfl_xor(v, 1));
                v = fmaxf(v, __shfl_xor(v, 2));
                v = fmaxf(v, __shfl_xor(v, 4));
                v = fmaxf(v, __shfl_xor(v, 8));
                float newm = fmaxf(m_[r], v);
                float corr = __expf(m_[r] - newm);
                float ps = 0.f;
                int q = l4 * 4 + r;
#pragma unroll
                for (int kc = 0; kc < 4; ++kc) {
                    float p = __expf(sv[kc][r] - newm);
                    ps += p;
                    int chunk = kc * 2 + (l15 >> 3);
                    int idx = q * 64 + ((chunk ^ (q & 7)) << 3) + (l15 & 7);
                    Pb[w][idx] = f2bf(p);
                }
                ps += __shfl_xor(ps, 1);
                ps += __shfl_xor(ps, 2);
                ps += __shfl_xor(ps, 4);
                ps += __shfl_xor(ps, 8);
                l_[r] = l_[r] * corr + ps;
                m_[r] = newm;
#pragma unroll
                for (int db = 0; db < 4; db++) o[db][r] *= corr;
            }

            asm volatile("s_waitcnt lgkmcnt(0)" ::: "memory");
            __builtin_amdgcn_sched_barrier(0);

            // ---- P * V ----
#pragma unroll
            for (int kg = 0; kg < 2; kg++) {
                bf16x8 pa = *(const bf16x8*)&Pb[w][l15 * 64 + (((kg * 4 + l4) ^ (l15 & 7)) << 3)];
#pragma unroll
                for (int db = 0; db < 4; db++) {
                    int d = db * 16 + l15;
                    bf16x8 vb = *(const bf16x8*)&Vt[cur][d * 64 + (((kg * 4 + l4) ^ (d & 7)) << 3)];
                    o[db] = __builtin_amdgcn_mfma_f32_16x16x32_bf16(pa, vb, o[db], 0, 0, 0);
                }
            }
        }

        // ---- finish staging tile kt+1 ----
        if (havenext) {
            asm volatile("s_waitcnt vmcnt(0)" ::: "memory");
            u16 av[4], bv[4];
            *(u32x2*)av = va; *(u32x2*)bv = vb_;
#pragma unroll
            for (int j = 0; j < 4; j++) {
                int d = vsd + j;
                unsigned int word = (unsigned int)av[j] | ((unsigned int)bv[j] << 16);
                int idx = d * 64 + ((((2 * vi) >> 3) ^ (d & 7)) << 3) + ((2 * vi) & 7);
                *(unsigned int*)&Vt[cur ^ 1][idx] = word;
            }
        }
        __syncthreads();
        cur ^= 1;
    }

#pragma unroll
    for (int r = 0; r < 4; r++) {
        float rcp = 1.f / l_[r];
        int qg = q0 + w * 16 + l4 * 4 + r;
        u16* yrow = y + (size_t)(b * Nn + qg) * Dd + h * DHd;
#pragma unroll
        for (int db = 0; db < 4; db++)
            yrow[db * 16 + l15] = f2bf(o[db][r] * rcp);
    }
}

extern "C" void kernel_launch(void* const* d_in, const int* in_sizes, int n_in,
                              void* d_out, int out_size, void* d_ws, size_t ws_size,
                              hipStream_t stream) {
    const float* x = (const float*)d_in[0];
    const float* Wqkv = (const float*)d_in[1];
    const float* Wout = (const float*)d_in[2];

    char* ws = (char*)d_ws;
    size_t off = 0;
    u16* xb = (u16*)(ws + off);    off += (size_t)Mm * Dd * 2;     // 16 MiB
    u16* wqkvb = (u16*)(ws + off); off += (size_t)D3 * Dd * 2;     //  6 MiB
    u16* woutb = (u16*)(ws + off); off += (size_t)Dd * Dd * 2;     //  2 MiB
    u16* qkv = (u16*)(ws + off);   off += (size_t)Mm * D3 * 2;     // 48 MiB
    u16* yb = (u16*)(ws + off);    off += (size_t)Mm * Dd * 2;     // 16 MiB

    cvt_f32_bf16<<<4096, 256, 0, stream>>>(x, xb, Mm * Dd / 4);
    cvt_f32_bf16<<<1024, 256, 0, stream>>>(Wqkv, wqkvb, D3 * Dd / 4);
    cvt_f32_bf16<<<512, 256, 0, stream>>>(Wout, woutb, Dd * Dd / 4);

    gemm_bt<0><<<dim3(D3 / 128, Mm / 128), 256, 0, stream>>>(xb, wqkvb, qkv, Mm, D3, Dd);
    attn<<<dim3(Nn / 128, Bb * Hh), 512, 0, stream>>>(qkv, yb);
    gemm_bt<1><<<dim3(Dd / 128, Mm / 128), 256, 0, stream>>>(yb, woutb, d_out, Mm, Dd, Dd);
}

// Round 5
// 291.582 us; speedup vs baseline: 1.5309x; 1.1098x over previous
//
#include <hip/hip_runtime.h>
#include <hip/hip_bf16.h>
#include <stdint.h>

#define Bb 4
#define Nn 2048
#define Dd 1024
#define Hh 16
#define DHd 64
#define Mm (Bb*Nn)     /* 8192 */
#define D3 (3*Dd)      /* 3072 */

typedef unsigned short u16;
typedef __attribute__((ext_vector_type(8))) short bf16x8;
typedef __attribute__((ext_vector_type(4))) float f32x4;
typedef __attribute__((ext_vector_type(2))) unsigned int u32x2;
typedef __attribute__((ext_vector_type(4))) unsigned int u32x4;

__device__ __forceinline__ u16 f2bf(float f) {
    unsigned int u = __float_as_uint(f);
    u = (u + 0x7FFFu + ((u >> 16) & 1u)) >> 16;
    return (u16)u;
}

#define GLOAD16(g, l)                                                          \
    __builtin_amdgcn_global_load_lds(                                          \
        (const __attribute__((address_space(1))) unsigned int*)(g),            \
        (__attribute__((address_space(3))) unsigned int*)(l), 16, 0, 0)

// ---------------- fp32 -> bf16 convert ----------------
__global__ void cvt_f32_bf16(const float* __restrict__ in, u16* __restrict__ out, int n4) {
    int i = blockIdx.x * blockDim.x + threadIdx.x;
    int stride = gridDim.x * blockDim.x;
    for (; i < n4; i += stride) {
        float4 v = ((const float4*)in)[i];
        u16 o0 = f2bf(v.x), o1 = f2bf(v.y), o2 = f2bf(v.z), o3 = f2bf(v.w);
        unsigned int lo = (unsigned int)o0 | ((unsigned int)o1 << 16);
        unsigned int hi = (unsigned int)o2 | ((unsigned int)o3 << 16);
        ((uint2*)out)[i] = make_uint2(lo, hi);
    }
}

// ---------------- bf16 GEMM: C[M][N] = A[M][K] * B[N][K]^T ----------------
template<int OUT_F32>
__global__ __launch_bounds__(256) void gemm_bt(const u16* __restrict__ A,
                                               const u16* __restrict__ Bm,
                                               void* __restrict__ C,
                                               int M, int Nout, int K) {
    __shared__ u16 As[128 * 32];
    __shared__ u16 Bs[128 * 32];
    const int t = threadIdx.x;
    const int lane = t & 63;
    const int w = t >> 6;
    const int wr = w >> 1, wc = w & 1;
    const int l15 = lane & 15, l4 = lane >> 4;
    const int m0 = blockIdx.y * 128;
    const int n0 = blockIdx.x * 128;

    f32x4 acc[4][4] = {};

    const int srow = t >> 2;
    const int scol = (t & 3) * 8;

    const u16* Ag0 = A + (size_t)(m0 + srow) * K + scol;
    const u16* Ag1 = A + (size_t)(m0 + 64 + srow) * K + scol;
    const u16* Bg0 = Bm + (size_t)(n0 + srow) * K + scol;
    const u16* Bg1 = Bm + (size_t)(n0 + 64 + srow) * K + scol;

    for (int k0 = 0; k0 < K; k0 += 32) {
        __syncthreads();
        GLOAD16(Ag0 + k0, &As[t * 8]);
        GLOAD16(Ag1 + k0, &As[2048 + t * 8]);
        GLOAD16(Bg0 + k0, &Bs[t * 8]);
        GLOAD16(Bg1 + k0, &Bs[2048 + t * 8]);
        __syncthreads();

        bf16x8 a[4], b[4];
#pragma unroll
        for (int mi = 0; mi < 4; mi++)
            a[mi] = *(const bf16x8*)&As[(wr * 64 + mi * 16 + l15) * 32 + l4 * 8];
#pragma unroll
        for (int nj = 0; nj < 4; nj++)
            b[nj] = *(const bf16x8*)&Bs[(wc * 64 + nj * 16 + l15) * 32 + l4 * 8];
#pragma unroll
        for (int mi = 0; mi < 4; mi++)
#pragma unroll
            for (int nj = 0; nj < 4; nj++)
                acc[mi][nj] = __builtin_amdgcn_mfma_f32_16x16x32_bf16(a[mi], b[nj], acc[mi][nj], 0, 0, 0);
    }

#pragma unroll
    for (int mi = 0; mi < 4; mi++) {
#pragma unroll
        for (int nj = 0; nj < 4; nj++) {
            int col = n0 + wc * 64 + nj * 16 + l15;
#pragma unroll
            for (int r = 0; r < 4; r++) {
                int row = m0 + wr * 64 + mi * 16 + l4 * 4 + r;
                float v = acc[mi][nj][r];
                if (OUT_F32)
                    ((float*)C)[(size_t)row * Nout + col] = v;
                else
                    ((u16*)C)[(size_t)row * Nout + col] = f2bf(v);
            }
        }
    }
}

// ---------------- causal flash attention ----------------
// grid: (8, B*H). 512 threads = 8 waves. Each block processes TWO q-tiles
// (qt = bid and 15-bid) for uniform work (34 k-tile iterations per block).
// K,V double-buffered; K via global_load_lds w/ pre-swizzled global src;
// V reg-staged transpose. All LDS XOR-swizzled at 16B chunks: chunk ^= (row&7).
__global__ __launch_bounds__(512) void attn(const u16* __restrict__ qkv, u16* __restrict__ y) {
    __shared__ u16 Kt[2][64 * 64];     // [buf][krow][d]  swizzled
    __shared__ u16 Vt[2][64 * 64];     // [buf][d][krow]  swizzled
    __shared__ u16 Pb[8][16 * 64];     // per-wave P [qrow][k]  swizzled

    const int t = threadIdx.x;
    const int lane = t & 63;
    const int w = t >> 6;
    const int l15 = lane & 15, l4 = lane >> 4;
    const int bh = blockIdx.y;
    const int b = bh >> 4, h = bh & 15;

    const u16* qbase = qkv + (size_t)(b * Nn) * D3 + h * DHd;
    const u16* Kg = qbase + Dd;
    const u16* Vg = qbase + 2 * Dd;

    // staging maps
    const int krow = t >> 3;            // K: 512 chunks of 16B, row 0..63
    const int kccol = t & 7;
    const int vi = t & 31;              // V: row pair (2vi, 2vi+1)
    const int vsd = (t >> 5) * 4;       // dims vsd..vsd+3

    for (int pass = 0; pass < 2; ++pass) {
        const int qt = pass == 0 ? (int)blockIdx.x : (int)(gridDim.x * 2 - 1 - blockIdx.x);
        const int q0 = qt * 128;
        const int ktmax = 2 * qt + 1;

        // Q fragments for this wave (rows q0 + w*16 + l15)
        bf16x8 qf[2];
        {
            const u16* qrow = qbase + (size_t)(q0 + w * 16 + l15) * D3;
            qf[0] = *(const bf16x8*)(qrow + l4 * 8);
            qf[1] = *(const bf16x8*)(qrow + 32 + l4 * 8);
        }

        f32x4 o[4] = {};
        float m_[4] = {-1e30f, -1e30f, -1e30f, -1e30f};
        float l_[4] = {0.f, 0.f, 0.f, 0.f};

        u32x2 va, vb_;

        // ---- prologue: stage tile 0 into buf 0 ----
        {
            const u16* src = Kg + (size_t)krow * D3 + ((kccol ^ (krow & 7)) << 3);
            GLOAD16(src, &Kt[0][t * 8]);
            const u16* vr0 = Vg + (size_t)(2 * vi) * D3 + vsd;
            va = *(const u32x2*)vr0;
            vb_ = *(const u32x2*)(vr0 + D3);
        }
        asm volatile("s_waitcnt vmcnt(0)" ::: "memory");
        {
            u16 av[4], bv[4];
            *(u32x2*)av = va; *(u32x2*)bv = vb_;
#pragma unroll
            for (int j = 0; j < 4; j++) {
                int d = vsd + j;
                unsigned int word = (unsigned int)av[j] | ((unsigned int)bv[j] << 16);
                int idx = d * 64 + ((((2 * vi) >> 3) ^ (d & 7)) << 3) + ((2 * vi) & 7);
                *(unsigned int*)&Vt[0][idx] = word;
            }
        }
        __syncthreads();

        int cur = 0;
        for (int kt = 0; kt <= ktmax; ++kt) {
            const int k0 = kt * 64;
            const int havenext = (kt < ktmax);

            // ---- issue prefetch of tile kt+1 into buf cur^1 ----
            if (havenext) {
                const int nk0 = k0 + 64;
                const u16* src = Kg + (size_t)(nk0 + krow) * D3 + ((kccol ^ (krow & 7)) << 3);
                GLOAD16(src, &Kt[cur ^ 1][t * 8]);
                const u16* vr0 = Vg + (size_t)(nk0 + 2 * vi) * D3 + vsd;
                va = *(const u32x2*)vr0;
                vb_ = *(const u32x2*)(vr0 + D3);
            }

            const int qwmin = q0 + w * 16;
            const int skip = (k0 > qwmin + 15);

            if (!skip) {
                const int needmask = (k0 + 63 > qwmin);

                // ---- QK^T: four 16-col S slices ----
                f32x4 sv[4];
                __builtin_amdgcn_s_setprio(1);
#pragma unroll
                for (int kc = 0; kc < 4; ++kc) {
                    f32x4 s = {};
                    int row = kc * 16 + l15;
                    int sw = (row & 7);
                    bf16x8 kf0 = *(const bf16x8*)&Kt[cur][row * 64 + ((l4 ^ sw) << 3)];
                    bf16x8 kf1 = *(const bf16x8*)&Kt[cur][row * 64 + (((4 + l4) ^ sw) << 3)];
                    s = __builtin_amdgcn_mfma_f32_16x16x32_bf16(qf[0], kf0, s, 0, 0, 0);
                    s = __builtin_amdgcn_mfma_f32_16x16x32_bf16(qf[1], kf1, s, 0, 0, 0);
#pragma unroll
                    for (int r = 0; r < 4; r++) {
                        float x = s[r] * 0.125f;
                        if (needmask) {
                            int kg = k0 + kc * 16 + l15;
                            int qg = qwmin + l4 * 4 + r;
                            if (kg > qg) x = -1e30f;
                        }
                        sv[kc][r] = x;
                    }
                }
                __builtin_amdgcn_s_setprio(0);

                // ---- online softmax over the 64 cols ----
#pragma unroll
                for (int r = 0; r < 4; r++) {
                    float v = fmaxf(fmaxf(sv[0][r], sv[1][r]), fmaxf(sv[2][r], sv[3][r]));
                    v = fmaxf(v, __shfl_xor(v, 1));
                    v = fmaxf(v, __shfl_xor(v, 2));
                    v = fmaxf(v, __shfl_xor(v, 4));
                    v = fmaxf(v, __shfl_xor(v, 8));
                    float newm = fmaxf(m_[r], v);
                    float corr = __expf(m_[r] - newm);
                    float ps = 0.f;
                    int q = l4 * 4 + r;
#pragma unroll
                    for (int kc = 0; kc < 4; ++kc) {
                        float p = __expf(sv[kc][r] - newm);
                        ps += p;
                        int chunk = kc * 2 + (l15 >> 3);
                        int idx = q * 64 + ((chunk ^ (q & 7)) << 3) + (l15 & 7);
                        Pb[w][idx] = f2bf(p);
                    }
                    ps += __shfl_xor(ps, 1);
                    ps += __shfl_xor(ps, 2);
                    ps += __shfl_xor(ps, 4);
                    ps += __shfl_xor(ps, 8);
                    l_[r] = l_[r] * corr + ps;
                    m_[r] = newm;
#pragma unroll
                    for (int db = 0; db < 4; db++) o[db][r] *= corr;
                }

                asm volatile("s_waitcnt lgkmcnt(0)" ::: "memory");
                __builtin_amdgcn_sched_barrier(0);

                // ---- P * V ----
                __builtin_amdgcn_s_setprio(1);
#pragma unroll
                for (int kg = 0; kg < 2; kg++) {
                    bf16x8 pa = *(const bf16x8*)&Pb[w][l15 * 64 + (((kg * 4 + l4) ^ (l15 & 7)) << 3)];
#pragma unroll
                    for (int db = 0; db < 4; db++) {
                        int d = db * 16 + l15;
                        bf16x8 vb = *(const bf16x8*)&Vt[cur][d * 64 + (((kg * 4 + l4) ^ (d & 7)) << 3)];
                        o[db] = __builtin_amdgcn_mfma_f32_16x16x32_bf16(pa, vb, o[db], 0, 0, 0);
                    }
                }
                __builtin_amdgcn_s_setprio(0);
            }

            // ---- finish staging tile kt+1 ----
            if (havenext) {
                asm volatile("s_waitcnt vmcnt(0)" ::: "memory");
                u16 av[4], bv[4];
                *(u32x2*)av = va; *(u32x2*)bv = vb_;
#pragma unroll
                for (int j = 0; j < 4; j++) {
                    int d = vsd + j;
                    unsigned int word = (unsigned int)av[j] | ((unsigned int)bv[j] << 16);
                    int idx = d * 64 + ((((2 * vi) >> 3) ^ (d & 7)) << 3) + ((2 * vi) & 7);
                    *(unsigned int*)&Vt[cur ^ 1][idx] = word;
                }
            }
            __syncthreads();
            cur ^= 1;
        }

        // ---- epilogue: write y for this pass ----
#pragma unroll
        for (int r = 0; r < 4; r++) {
            float rcp = 1.f / l_[r];
            int qg = q0 + w * 16 + l4 * 4 + r;
            u16* yrow = y + (size_t)(b * Nn + qg) * Dd + h * DHd;
#pragma unroll
            for (int db = 0; db < 4; db++)
                yrow[db * 16 + l15] = f2bf(o[db][r] * rcp);
        }
    }
}

extern "C" void kernel_launch(void* const* d_in, const int* in_sizes, int n_in,
                              void* d_out, int out_size, void* d_ws, size_t ws_size,
                              hipStream_t stream) {
    const float* x = (const float*)d_in[0];
    const float* Wqkv = (const float*)d_in[1];
    const float* Wout = (const float*)d_in[2];

    char* ws = (char*)d_ws;
    size_t off = 0;
    u16* xb = (u16*)(ws + off);    off += (size_t)Mm * Dd * 2;     // 16 MiB
    u16* wqkvb = (u16*)(ws + off); off += (size_t)D3 * Dd * 2;     //  6 MiB
    u16* woutb = (u16*)(ws + off); off += (size_t)Dd * Dd * 2;     //  2 MiB
    u16* qkv = (u16*)(ws + off);   off += (size_t)Mm * D3 * 2;     // 48 MiB
    u16* yb = (u16*)(ws + off);    off += (size_t)Mm * Dd * 2;     // 16 MiB

    cvt_f32_bf16<<<4096, 256, 0, stream>>>(x, xb, Mm * Dd / 4);
    cvt_f32_bf16<<<1024, 256, 0, stream>>>(Wqkv, wqkvb, D3 * Dd / 4);
    cvt_f32_bf16<<<512, 256, 0, stream>>>(Wout, woutb, Dd * Dd / 4);

    gemm_bt<0><<<dim3(D3 / 128, Mm / 128), 256, 0, stream>>>(xb, wqkvb, qkv, Mm, D3, Dd);
    attn<<<dim3(Nn / 256, Bb * Hh), 512, 0, stream>>>(qkv, yb);
    gemm_bt<1><<<dim3(Dd / 128, Mm / 128), 256, 0, stream>>>(yb, woutb, d_out, Mm, Dd, Dd);
}

// Round 6
// 218.373 us; speedup vs baseline: 2.0441x; 1.3352x over previous
//
#include <hip/hip_runtime.h>
#include <hip/hip_bf16.h>
#include <stdint.h>

#define Bb 4
#define Nn 2048
#define Dd 1024
#define Hh 16
#define DHd 64
#define Mm (Bb*Nn)     /* 8192 */
#define D3 (3*Dd)      /* 3072 */

typedef unsigned short u16;
typedef unsigned int u32;
typedef __attribute__((ext_vector_type(8))) short bf16x8;
typedef __attribute__((ext_vector_type(4))) float f32x4;
typedef __attribute__((ext_vector_type(2))) unsigned int u32x2;
typedef __attribute__((ext_vector_type(4))) unsigned int u32x4;

__device__ __forceinline__ u16 f2bf(float f) {
    unsigned int u = __float_as_uint(f);
    u = (u + 0x7FFFu + ((u >> 16) & 1u)) >> 16;
    return (u16)u;
}

__device__ __forceinline__ u32 cvtpk_bf16(float lo, float hi) {
    u32 r;
    asm("v_cvt_pk_bf16_f32 %0, %1, %2" : "=v"(r) : "v"(lo), "v"(hi));
    return r;
}

#define GLOAD16(g, l)                                                          \
    __builtin_amdgcn_global_load_lds(                                          \
        (const __attribute__((address_space(1))) unsigned int*)(g),            \
        (__attribute__((address_space(3))) unsigned int*)(l), 16, 0, 0)

// ---------------- fp32 -> bf16 convert ----------------
__global__ void cvt_f32_bf16(const float* __restrict__ in, u16* __restrict__ out, int n4) {
    int i = blockIdx.x * blockDim.x + threadIdx.x;
    int stride = gridDim.x * blockDim.x;
    for (; i < n4; i += stride) {
        float4 v = ((const float4*)in)[i];
        u16 o0 = f2bf(v.x), o1 = f2bf(v.y), o2 = f2bf(v.z), o3 = f2bf(v.w);
        unsigned int lo = (unsigned int)o0 | ((unsigned int)o1 << 16);
        unsigned int hi = (unsigned int)o2 | ((unsigned int)o3 << 16);
        ((uint2*)out)[i] = make_uint2(lo, hi);
    }
}

// ---------------- bf16 GEMM: C[M][N] = A[M][K] * B[N][K]^T ----------------
template<int OUT_F32>
__global__ __launch_bounds__(256) void gemm_bt(const u16* __restrict__ A,
                                               const u16* __restrict__ Bm,
                                               void* __restrict__ C,
                                               int M, int Nout, int K) {
    __shared__ u16 As[128 * 32];
    __shared__ u16 Bs[128 * 32];
    const int t = threadIdx.x;
    const int lane = t & 63;
    const int w = t >> 6;
    const int wr = w >> 1, wc = w & 1;
    const int l15 = lane & 15, l4 = lane >> 4;
    const int m0 = blockIdx.y * 128;
    const int n0 = blockIdx.x * 128;

    f32x4 acc[4][4] = {};

    const int srow = t >> 2;
    const int scol = (t & 3) * 8;

    const u16* Ag0 = A + (size_t)(m0 + srow) * K + scol;
    const u16* Ag1 = A + (size_t)(m0 + 64 + srow) * K + scol;
    const u16* Bg0 = Bm + (size_t)(n0 + srow) * K + scol;
    const u16* Bg1 = Bm + (size_t)(n0 + 64 + srow) * K + scol;

    for (int k0 = 0; k0 < K; k0 += 32) {
        __syncthreads();
        GLOAD16(Ag0 + k0, &As[t * 8]);
        GLOAD16(Ag1 + k0, &As[2048 + t * 8]);
        GLOAD16(Bg0 + k0, &Bs[t * 8]);
        GLOAD16(Bg1 + k0, &Bs[2048 + t * 8]);
        __syncthreads();

        bf16x8 a[4], b[4];
#pragma unroll
        for (int mi = 0; mi < 4; mi++)
            a[mi] = *(const bf16x8*)&As[(wr * 64 + mi * 16 + l15) * 32 + l4 * 8];
#pragma unroll
        for (int nj = 0; nj < 4; nj++)
            b[nj] = *(const bf16x8*)&Bs[(wc * 64 + nj * 16 + l15) * 32 + l4 * 8];
#pragma unroll
        for (int mi = 0; mi < 4; mi++)
#pragma unroll
            for (int nj = 0; nj < 4; nj++)
                acc[mi][nj] = __builtin_amdgcn_mfma_f32_16x16x32_bf16(a[mi], b[nj], acc[mi][nj], 0, 0, 0);
    }

#pragma unroll
    for (int mi = 0; mi < 4; mi++) {
#pragma unroll
        for (int nj = 0; nj < 4; nj++) {
            int col = n0 + wc * 64 + nj * 16 + l15;
#pragma unroll
            for (int r = 0; r < 4; r++) {
                int row = m0 + wr * 64 + mi * 16 + l4 * 4 + r;
                float v = acc[mi][nj][r];
                if (OUT_F32)
                    ((float*)C)[(size_t)row * Nout + col] = v;
                else
                    ((u16*)C)[(size_t)row * Nout + col] = f2bf(v);
            }
        }
    }
}

// ---------------- causal flash attention ----------------
// grid: (8, B*H). 512 threads = 8 waves; each block does q-tiles bid and 15-bid.
// Swapped QK^T: S^T = mfma(K,Q) -> lane holds S[k=kc*16+l4*4+r][q=l15].
// Softmax in-register (per-lane m_,l_ for q=l15); P repacked to PV A-fragments
// via cvt_pk_bf16 + xor-shfl butterfly (no LDS round trip).
__global__ __launch_bounds__(512) void attn(const u16* __restrict__ qkv, u16* __restrict__ y) {
    __shared__ u16 Kt[2][64 * 64];     // [buf][krow][d]  swizzled 16B chunks: chunk^=(row&7)
    __shared__ u16 Vt[2][64 * 64];     // [buf][d][krow]  swizzled

    const int t = threadIdx.x;
    const int lane = t & 63;
    const int w = t >> 6;
    const int l15 = lane & 15, l4 = lane >> 4;
    const int bh = blockIdx.y;
    const int b = bh >> 4, h = bh & 15;

    const u16* qbase = qkv + (size_t)(b * Nn) * D3 + h * DHd;
    const u16* Kg = qbase + Dd;
    const u16* Vg = qbase + 2 * Dd;

    // staging maps
    const int krow = t >> 3;            // K: 512 chunks of 16B, row 0..63
    const int kccol = t & 7;
    const int vi = t & 31;              // V: row pair (2vi, 2vi+1)
    const int vsd = (t >> 5) * 4;       // dims vsd..vsd+3

    const bool hi2 = (lane >> 5) & 1;   // l4>>1
    const bool bit0 = (lane >> 4) & 1;  // l4&1
    const int sgrp = lane & 48;         // l4<<4

    const float SCL = 0.18033688011f;   // 0.125 * log2(e)

    for (int pass = 0; pass < 2; ++pass) {
        const int qt = pass == 0 ? (int)blockIdx.x : (int)(gridDim.x * 2 - 1 - blockIdx.x);
        const int q0 = qt * 128;
        const int ktmax = 2 * qt + 1;

        // Q fragments (A-layout rows q0+w*16+l15 when used as B-operand: col=q)
        bf16x8 qf[2];
        {
            const u16* qrow = qbase + (size_t)(q0 + w * 16 + l15) * D3;
            qf[0] = *(const bf16x8*)(qrow + l4 * 8);
            qf[1] = *(const bf16x8*)(qrow + 32 + l4 * 8);
        }

        f32x4 o[4] = {};
        float m_ = -1e30f;   // per q = l15 (uniform across 4-lane group)
        float l_ = 0.f;

        u32x2 va, vb_;

        // ---- prologue: stage tile 0 into buf 0 ----
        {
            const u16* src = Kg + (size_t)krow * D3 + ((kccol ^ (krow & 7)) << 3);
            GLOAD16(src, &Kt[0][t * 8]);
            const u16* vr0 = Vg + (size_t)(2 * vi) * D3 + vsd;
            va = *(const u32x2*)vr0;
            vb_ = *(const u32x2*)(vr0 + D3);
        }
        asm volatile("s_waitcnt vmcnt(0)" ::: "memory");
        {
            u16 av[4], bv[4];
            *(u32x2*)av = va; *(u32x2*)bv = vb_;
#pragma unroll
            for (int j = 0; j < 4; j++) {
                int d = vsd + j;
                unsigned int word = (unsigned int)av[j] | ((unsigned int)bv[j] << 16);
                int idx = d * 64 + ((((2 * vi) >> 3) ^ (d & 7)) << 3) + ((2 * vi) & 7);
                *(unsigned int*)&Vt[0][idx] = word;
            }
        }
        __syncthreads();

        int cur = 0;
        for (int kt = 0; kt <= ktmax; ++kt) {
            const int k0 = kt * 64;
            const int havenext = (kt < ktmax);

            // ---- issue prefetch of tile kt+1 into buf cur^1 ----
            if (havenext) {
                const int nk0 = k0 + 64;
                const u16* src = Kg + (size_t)(nk0 + krow) * D3 + ((kccol ^ (krow & 7)) << 3);
                GLOAD16(src, &Kt[cur ^ 1][t * 8]);
                const u16* vr0 = Vg + (size_t)(nk0 + 2 * vi) * D3 + vsd;
                va = *(const u32x2*)vr0;
                vb_ = *(const u32x2*)(vr0 + D3);
            }

            const int qwmin = q0 + w * 16;
            const int skip = (k0 > qwmin + 15);

            if (!skip) {
                const int needmask = (k0 + 63 > qwmin);

                // ---- QK^T (swapped): sv[kc][r] = S[k0+kc*16+l4*4+r][q=qwmin+l15]
                f32x4 sv[4];
                __builtin_amdgcn_s_setprio(1);
#pragma unroll
                for (int kc = 0; kc < 4; ++kc) {
                    f32x4 s = {};
                    int row = kc * 16 + l15;
                    int sw = (row & 7);
                    bf16x8 kf0 = *(const bf16x8*)&Kt[cur][row * 64 + ((l4 ^ sw) << 3)];
                    bf16x8 kf1 = *(const bf16x8*)&Kt[cur][row * 64 + (((4 + l4) ^ sw) << 3)];
                    s = __builtin_amdgcn_mfma_f32_16x16x32_bf16(kf0, qf[0], s, 0, 0, 0);
                    s = __builtin_amdgcn_mfma_f32_16x16x32_bf16(kf1, qf[1], s, 0, 0, 0);
#pragma unroll
                    for (int r = 0; r < 4; r++) {
                        float x = s[r] * SCL;
                        if (needmask) {
                            int kg = k0 + kc * 16 + l4 * 4 + r;
                            int qg = qwmin + l15;
                            if (kg > qg) x = -1e30f;
                        }
                        sv[kc][r] = x;
                    }
                }
                __builtin_amdgcn_s_setprio(0);

                // ---- softmax (log2 domain), per q = l15 ----
                float v = sv[0][0];
#pragma unroll
                for (int kc = 0; kc < 4; ++kc)
#pragma unroll
                    for (int r = 0; r < 4; ++r)
                        v = fmaxf(v, sv[kc][r]);
                v = fmaxf(v, __shfl_xor(v, 16));
                v = fmaxf(v, __shfl_xor(v, 32));

                if (!__all(v <= m_ + 8.f)) {     // T13 defer-max
                    float newm = fmaxf(m_, v);
                    float corr = exp2f(m_ - newm);
                    l_ *= corr;
                    float corr_o[4];
#pragma unroll
                    for (int r = 0; r < 4; ++r)
                        corr_o[r] = __shfl(corr, sgrp | (((lane >> 4) & 3) * 4 + r));
#pragma unroll
                    for (int db = 0; db < 4; db++)
#pragma unroll
                        for (int r = 0; r < 4; r++) o[db][r] *= corr_o[r];
                    m_ = newm;
                }

                float ps = 0.f;
#pragma unroll
                for (int kc = 0; kc < 4; ++kc)
#pragma unroll
                    for (int r = 0; r < 4; ++r) {
                        float p = exp2f(sv[kc][r] - m_);
                        sv[kc][r] = p;
                        ps += p;
                    }
                ps += __shfl_xor(ps, 16);
                ps += __shfl_xor(ps, 32);
                l_ += ps;

                // ---- pack P to bf16 pairs: up[kc][s] = (k=base+2s, base+2s+1)
                u32 up[4][2];
#pragma unroll
                for (int kc = 0; kc < 4; ++kc) {
                    up[kc][0] = cvtpk_bf16(sv[kc][0], sv[kc][1]);
                    up[kc][1] = cvtpk_bf16(sv[kc][2], sv[kc][3]);
                }

                // ---- transpose network + PV ----
                __builtin_amdgcn_s_setprio(1);
#pragma unroll
                for (int kg = 0; kg < 2; kg++) {
                    // payloads: pay_a = up[2kg + hi2], pay_b = up[2kg + !hi2]
                    u32 paya0 = hi2 ? up[2 * kg + 1][0] : up[2 * kg][0];
                    u32 paya1 = hi2 ? up[2 * kg + 1][1] : up[2 * kg][1];
                    u32 payb0 = hi2 ? up[2 * kg][0] : up[2 * kg + 1][0];
                    u32 payb1 = hi2 ? up[2 * kg][1] : up[2 * kg + 1][1];
                    u32 a16_0 = (u32)__shfl_xor((int)paya0, 16);
                    u32 a16_1 = (u32)__shfl_xor((int)paya1, 16);
                    u32 a32_0 = (u32)__shfl_xor((int)payb0, 32);
                    u32 a32_1 = (u32)__shfl_xor((int)payb1, 32);
                    u32 a48_0 = (u32)__shfl_xor((int)payb0, 48);
                    u32 a48_1 = (u32)__shfl_xor((int)payb1, 48);
                    // assemble A-fragment: t[j] = k-pair (kg*32 + l4*8 + 2j)
                    u32x4 tt;
                    tt[0] = hi2 ? (bit0 ? a16_0 : a32_0) : (bit0 ? a48_0 : paya0);
                    tt[1] = hi2 ? (bit0 ? a16_1 : a32_1) : (bit0 ? a48_1 : paya1);
                    tt[2] = hi2 ? (bit0 ? paya0 : a48_0) : (bit0 ? a32_0 : a16_0);
                    tt[3] = hi2 ? (bit0 ? paya1 : a48_1) : (bit0 ? a32_1 : a16_1);
                    union { u32x4 u; bf16x8 b; } pa;
                    pa.u = tt;
#pragma unroll
                    for (int db = 0; db < 4; db++) {
                        int d = db * 16 + l15;
                        bf16x8 vb = *(const bf16x8*)&Vt[cur][d * 64 + (((kg * 4 + l4) ^ (d & 7)) << 3)];
                        o[db] = __builtin_amdgcn_mfma_f32_16x16x32_bf16(pa.b, vb, o[db], 0, 0, 0);
                    }
                }
                __builtin_amdgcn_s_setprio(0);
            }

            // ---- finish staging tile kt+1 ----
            if (havenext) {
                asm volatile("s_waitcnt vmcnt(0)" ::: "memory");
                u16 av[4], bv[4];
                *(u32x2*)av = va; *(u32x2*)bv = vb_;
#pragma unroll
                for (int j = 0; j < 4; j++) {
                    int d = vsd + j;
                    unsigned int word = (unsigned int)av[j] | ((unsigned int)bv[j] << 16);
                    int idx = d * 64 + ((((2 * vi) >> 3) ^ (d & 7)) << 3) + ((2 * vi) & 7);
                    *(unsigned int*)&Vt[cur ^ 1][idx] = word;
                }
            }
            __syncthreads();
            cur ^= 1;
        }

        // ---- epilogue: write y (o row q = l4*4+r needs l_ of lane l15=q) ----
        float linv = 1.f / l_;
        float linv_o[4];
#pragma unroll
        for (int r = 0; r < 4; ++r)
            linv_o[r] = __shfl(linv, sgrp | (((lane >> 4) & 3) * 4 + r));
#pragma unroll
        for (int r = 0; r < 4; r++) {
            int qg = q0 + w * 16 + l4 * 4 + r;
            u16* yrow = y + (size_t)(b * Nn + qg) * Dd + h * DHd;
#pragma unroll
            for (int db = 0; db < 4; db++)
                yrow[db * 16 + l15] = f2bf(o[db][r] * linv_o[r]);
        }
    }
}

extern "C" void kernel_launch(void* const* d_in, const int* in_sizes, int n_in,
                              void* d_out, int out_size, void* d_ws, size_t ws_size,
                              hipStream_t stream) {
    const float* x = (const float*)d_in[0];
    const float* Wqkv = (const float*)d_in[1];
    const float* Wout = (const float*)d_in[2];

    char* ws = (char*)d_ws;
    size_t off = 0;
    u16* xb = (u16*)(ws + off);    off += (size_t)Mm * Dd * 2;     // 16 MiB
    u16* wqkvb = (u16*)(ws + off); off += (size_t)D3 * Dd * 2;     //  6 MiB
    u16* woutb = (u16*)(ws + off); off += (size_t)Dd * Dd * 2;     //  2 MiB
    u16* qkv = (u16*)(ws + off);   off += (size_t)Mm * D3 * 2;     // 48 MiB
    u16* yb = (u16*)(ws + off);    off += (size_t)Mm * Dd * 2;     // 16 MiB

    cvt_f32_bf16<<<4096, 256, 0, stream>>>(x, xb, Mm * Dd / 4);
    cvt_f32_bf16<<<1024, 256, 0, stream>>>(Wqkv, wqkvb, D3 * Dd / 4);
    cvt_f32_bf16<<<512, 256, 0, stream>>>(Wout, woutb, Dd * Dd / 4);

    gemm_bt<0><<<dim3(D3 / 128, Mm / 128), 256, 0, stream>>>(xb, wqkvb, qkv, Mm, D3, Dd);
    attn<<<dim3(Nn / 256, Bb * Hh), 512, 0, stream>>>(qkv, yb);
    gemm_bt<1><<<dim3(Dd / 128, Mm / 128), 256, 0, stream>>>(yb, woutb, d_out, Mm, Dd, Dd);
}

// Round 7
// 204.953 us; speedup vs baseline: 2.1779x; 1.0655x over previous
//
#include <hip/hip_runtime.h>
#include <hip/hip_bf16.h>
#include <stdint.h>

#define Bb 4
#define Nn 2048
#define Dd 1024
#define Hh 16
#define DHd 64
#define Mm (Bb*Nn)     /* 8192 */
#define D3 (3*Dd)      /* 3072 */

typedef unsigned short u16;
typedef unsigned int u32;
typedef __attribute__((ext_vector_type(8))) short bf16x8;
typedef __attribute__((ext_vector_type(4))) float f32x4;
typedef __attribute__((ext_vector_type(2))) unsigned int u32x2;
typedef __attribute__((ext_vector_type(4))) unsigned int u32x4;

__device__ __forceinline__ u16 f2bf(float f) {
    unsigned int u = __float_as_uint(f);
    u = (u + 0x7FFFu + ((u >> 16) & 1u)) >> 16;
    return (u16)u;
}

__device__ __forceinline__ u32 cvtpk_bf16(float lo, float hi) {
    u32 r;
    asm("v_cvt_pk_bf16_f32 %0, %1, %2" : "=v"(r) : "v"(lo), "v"(hi));
    return r;
}

// bare HW exp2 — no libm guards (inputs bounded by defer-max; -huge underflows to 0)
__device__ __forceinline__ float fexp2(float x) {
    float r;
    asm("v_exp_f32 %0, %1" : "=v"(r) : "v"(x));
    return r;
}

#define GLOAD16(g, l)                                                          \
    __builtin_amdgcn_global_load_lds(                                          \
        (const __attribute__((address_space(1))) unsigned int*)(g),            \
        (__attribute__((address_space(3))) unsigned int*)(l), 16, 0, 0)

// ---------------- fp32 -> bf16 convert ----------------
__global__ void cvt_f32_bf16(const float* __restrict__ in, u16* __restrict__ out, int n4) {
    int i = blockIdx.x * blockDim.x + threadIdx.x;
    int stride = gridDim.x * blockDim.x;
    for (; i < n4; i += stride) {
        float4 v = ((const float4*)in)[i];
        u16 o0 = f2bf(v.x), o1 = f2bf(v.y), o2 = f2bf(v.z), o3 = f2bf(v.w);
        unsigned int lo = (unsigned int)o0 | ((unsigned int)o1 << 16);
        unsigned int hi = (unsigned int)o2 | ((unsigned int)o3 << 16);
        ((uint2*)out)[i] = make_uint2(lo, hi);
    }
}

// convert with scale s applied to flat elements [0, cut4*4) — folds softmax
// scale into the Q-projection rows of W_qkv
__global__ void cvt_f32_bf16_s(const float* __restrict__ in, u16* __restrict__ out,
                               int n4, int cut4, float s) {
    int i = blockIdx.x * blockDim.x + threadIdx.x;
    int stride = gridDim.x * blockDim.x;
    for (; i < n4; i += stride) {
        float4 v = ((const float4*)in)[i];
        float sc = (i < cut4) ? s : 1.0f;
        u16 o0 = f2bf(v.x * sc), o1 = f2bf(v.y * sc), o2 = f2bf(v.z * sc), o3 = f2bf(v.w * sc);
        unsigned int lo = (unsigned int)o0 | ((unsigned int)o1 << 16);
        unsigned int hi = (unsigned int)o2 | ((unsigned int)o3 << 16);
        ((uint2*)out)[i] = make_uint2(lo, hi);
    }
}

// ---------------- bf16 GEMM: C[M][N] = A[M][K] * B[N][K]^T ----------------
template<int OUT_F32>
__global__ __launch_bounds__(256) void gemm_bt(const u16* __restrict__ A,
                                               const u16* __restrict__ Bm,
                                               void* __restrict__ C,
                                               int M, int Nout, int K) {
    __shared__ u16 As[128 * 32];
    __shared__ u16 Bs[128 * 32];
    const int t = threadIdx.x;
    const int lane = t & 63;
    const int w = t >> 6;
    const int wr = w >> 1, wc = w & 1;
    const int l15 = lane & 15, l4 = lane >> 4;
    const int m0 = blockIdx.y * 128;
    const int n0 = blockIdx.x * 128;

    f32x4 acc[4][4] = {};

    const int srow = t >> 2;
    const int scol = (t & 3) * 8;

    const u16* Ag0 = A + (size_t)(m0 + srow) * K + scol;
    const u16* Ag1 = A + (size_t)(m0 + 64 + srow) * K + scol;
    const u16* Bg0 = Bm + (size_t)(n0 + srow) * K + scol;
    const u16* Bg1 = Bm + (size_t)(n0 + 64 + srow) * K + scol;

    for (int k0 = 0; k0 < K; k0 += 32) {
        __syncthreads();
        GLOAD16(Ag0 + k0, &As[t * 8]);
        GLOAD16(Ag1 + k0, &As[2048 + t * 8]);
        GLOAD16(Bg0 + k0, &Bs[t * 8]);
        GLOAD16(Bg1 + k0, &Bs[2048 + t * 8]);
        __syncthreads();

        bf16x8 a[4], b[4];
#pragma unroll
        for (int mi = 0; mi < 4; mi++)
            a[mi] = *(const bf16x8*)&As[(wr * 64 + mi * 16 + l15) * 32 + l4 * 8];
#pragma unroll
        for (int nj = 0; nj < 4; nj++)
            b[nj] = *(const bf16x8*)&Bs[(wc * 64 + nj * 16 + l15) * 32 + l4 * 8];
#pragma unroll
        for (int mi = 0; mi < 4; mi++)
#pragma unroll
            for (int nj = 0; nj < 4; nj++)
                acc[mi][nj] = __builtin_amdgcn_mfma_f32_16x16x32_bf16(a[mi], b[nj], acc[mi][nj], 0, 0, 0);
    }

#pragma unroll
    for (int mi = 0; mi < 4; mi++) {
#pragma unroll
        for (int nj = 0; nj < 4; nj++) {
            int col = n0 + wc * 64 + nj * 16 + l15;
#pragma unroll
            for (int r = 0; r < 4; r++) {
                int row = m0 + wr * 64 + mi * 16 + l4 * 4 + r;
                float v = acc[mi][nj][r];
                if (OUT_F32)
                    ((float*)C)[(size_t)row * Nout + col] = v;
                else
                    ((u16*)C)[(size_t)row * Nout + col] = f2bf(v);
            }
        }
    }
}

// ---------------- causal flash attention ----------------
// grid: (8, B*H). 512 threads = 8 waves; each block does q-tiles bid and 15-bid.
// Swapped QK^T: S^T = mfma(K,Q) -> lane holds S[k=kc*16+l4*4+r][q=l15], already
// in log2 domain (scale baked into W_q rows). Softmax in-register; P repacked
// to PV A-fragments via cvt_pk_bf16 + xor-shfl butterfly (no LDS round trip).
__global__ __launch_bounds__(512) void attn(const u16* __restrict__ qkv, u16* __restrict__ y) {
    __shared__ u16 Kt[2][64 * 64];     // [buf][krow][d]  swizzled 16B chunks: chunk^=(row&7)
    __shared__ u16 Vt[2][64 * 64];     // [buf][d][krow]  swizzled

    const int t = threadIdx.x;
    const int lane = t & 63;
    const int w = t >> 6;
    const int l15 = lane & 15, l4 = lane >> 4;
    const int bh = blockIdx.y;
    const int b = bh >> 4, h = bh & 15;

    const u16* qbase = qkv + (size_t)(b * Nn) * D3 + h * DHd;
    const u16* Kg = qbase + Dd;
    const u16* Vg = qbase + 2 * Dd;

    // staging maps
    const int krow = t >> 3;            // K: 512 chunks of 16B, row 0..63
    const int kccol = t & 7;
    const int vi = t & 31;              // V: row pair (2vi, 2vi+1)
    const int vsd = (t >> 5) * 4;       // dims vsd..vsd+3

    const bool hi2 = (lane >> 5) & 1;   // l4>>1
    const bool bit0 = (lane >> 4) & 1;  // l4&1
    const int sgrp = lane & 48;         // l4<<4

    for (int pass = 0; pass < 2; ++pass) {
        const int qt = pass == 0 ? (int)blockIdx.x : (int)(gridDim.x * 2 - 1 - blockIdx.x);
        const int q0 = qt * 128;
        const int ktmax = 2 * qt + 1;

        // Q fragments (used as B-operand: col = q)
        bf16x8 qf[2];
        {
            const u16* qrow = qbase + (size_t)(q0 + w * 16 + l15) * D3;
            qf[0] = *(const bf16x8*)(qrow + l4 * 8);
            qf[1] = *(const bf16x8*)(qrow + 32 + l4 * 8);
        }

        f32x4 o[4] = {};
        float m_ = -1e30f;   // per q = l15 (uniform across 4-lane group)
        float l_ = 0.f;      // per-lane PARTIAL sum; reduced once at epilogue

        u32x2 va, vb_;

        // ---- prologue: stage tile 0 into buf 0 ----
        {
            const u16* src = Kg + (size_t)krow * D3 + ((kccol ^ (krow & 7)) << 3);
            GLOAD16(src, &Kt[0][t * 8]);
            const u16* vr0 = Vg + (size_t)(2 * vi) * D3 + vsd;
            va = *(const u32x2*)vr0;
            vb_ = *(const u32x2*)(vr0 + D3);
        }
        asm volatile("s_waitcnt vmcnt(0)" ::: "memory");
        {
            u16 av[4], bv[4];
            *(u32x2*)av = va; *(u32x2*)bv = vb_;
#pragma unroll
            for (int j = 0; j < 4; j++) {
                int d = vsd + j;
                unsigned int word = (unsigned int)av[j] | ((unsigned int)bv[j] << 16);
                int idx = d * 64 + ((((2 * vi) >> 3) ^ (d & 7)) << 3) + ((2 * vi) & 7);
                *(unsigned int*)&Vt[0][idx] = word;
            }
        }
        __syncthreads();

        int cur = 0;
        for (int kt = 0; kt <= ktmax; ++kt) {
            const int k0 = kt * 64;
            const int havenext = (kt < ktmax);

            // ---- issue prefetch of tile kt+1 into buf cur^1 ----
            if (havenext) {
                const int nk0 = k0 + 64;
                const u16* src = Kg + (size_t)(nk0 + krow) * D3 + ((kccol ^ (krow & 7)) << 3);
                GLOAD16(src, &Kt[cur ^ 1][t * 8]);
                const u16* vr0 = Vg + (size_t)(nk0 + 2 * vi) * D3 + vsd;
                va = *(const u32x2*)vr0;
                vb_ = *(const u32x2*)(vr0 + D3);
            }

            const int qwmin = q0 + w * 16;
            const int skip = (k0 > qwmin + 15);

            if (!skip) {
                const int needmask = (k0 + 63 > qwmin);

                // ---- QK^T (swapped): sv[kc][r] = S[k0+kc*16+l4*4+r][q=qwmin+l15]
                f32x4 sv[4];
                __builtin_amdgcn_s_setprio(1);
#pragma unroll
                for (int kc = 0; kc < 4; ++kc) {
                    f32x4 s = {};
                    int row = kc * 16 + l15;
                    int sw = (row & 7);
                    bf16x8 kf0 = *(const bf16x8*)&Kt[cur][row * 64 + ((l4 ^ sw) << 3)];
                    bf16x8 kf1 = *(const bf16x8*)&Kt[cur][row * 64 + (((4 + l4) ^ sw) << 3)];
                    s = __builtin_amdgcn_mfma_f32_16x16x32_bf16(kf0, qf[0], s, 0, 0, 0);
                    s = __builtin_amdgcn_mfma_f32_16x16x32_bf16(kf1, qf[1], s, 0, 0, 0);
#pragma unroll
                    for (int r = 0; r < 4; r++) {
                        float x = s[r];
                        if (needmask) {
                            int kg = k0 + kc * 16 + l4 * 4 + r;
                            int qg = qwmin + l15;
                            if (kg > qg) x = -1e30f;
                        }
                        sv[kc][r] = x;
                    }
                }
                __builtin_amdgcn_s_setprio(0);

                // ---- softmax (log2 domain), per q = l15 ----
                float v = sv[0][0];
#pragma unroll
                for (int kc = 0; kc < 4; ++kc)
#pragma unroll
                    for (int r = 0; r < 4; ++r)
                        v = fmaxf(v, sv[kc][r]);
                v = fmaxf(v, __shfl_xor(v, 16));
                v = fmaxf(v, __shfl_xor(v, 32));

                if (!__all(v <= m_ + 8.f)) {     // T13 defer-max
                    float newm = fmaxf(m_, v);
                    float corr = fexp2(m_ - newm);
                    l_ *= corr;
                    float corr_o[4];
#pragma unroll
                    for (int r = 0; r < 4; ++r)
                        corr_o[r] = __shfl(corr, sgrp | (((lane >> 4) & 3) * 4 + r));
#pragma unroll
                    for (int db = 0; db < 4; db++)
#pragma unroll
                        for (int r = 0; r < 4; r++) o[db][r] *= corr_o[r];
                    m_ = newm;
                }

#pragma unroll
                for (int kc = 0; kc < 4; ++kc)
#pragma unroll
                    for (int r = 0; r < 4; ++r) {
                        float p = fexp2(sv[kc][r] - m_);
                        sv[kc][r] = p;
                        l_ += p;
                    }

                // ---- pack P to bf16 pairs ----
                u32 up[4][2];
#pragma unroll
                for (int kc = 0; kc < 4; ++kc) {
                    up[kc][0] = cvtpk_bf16(sv[kc][0], sv[kc][1]);
                    up[kc][1] = cvtpk_bf16(sv[kc][2], sv[kc][3]);
                }

                // ---- transpose network + PV ----
                __builtin_amdgcn_s_setprio(1);
#pragma unroll
                for (int kg = 0; kg < 2; kg++) {
                    u32 paya0 = hi2 ? up[2 * kg + 1][0] : up[2 * kg][0];
                    u32 paya1 = hi2 ? up[2 * kg + 1][1] : up[2 * kg][1];
                    u32 payb0 = hi2 ? up[2 * kg][0] : up[2 * kg + 1][0];
                    u32 payb1 = hi2 ? up[2 * kg][1] : up[2 * kg + 1][1];
                    u32 a16_0 = (u32)__shfl_xor((int)paya0, 16);
                    u32 a16_1 = (u32)__shfl_xor((int)paya1, 16);
                    u32 a32_0 = (u32)__shfl_xor((int)payb0, 32);
                    u32 a32_1 = (u32)__shfl_xor((int)payb1, 32);
                    u32 a48_0 = (u32)__shfl_xor((int)payb0, 48);
                    u32 a48_1 = (u32)__shfl_xor((int)payb1, 48);
                    u32x4 tt;
                    tt[0] = hi2 ? (bit0 ? a16_0 : a32_0) : (bit0 ? a48_0 : paya0);
                    tt[1] = hi2 ? (bit0 ? a16_1 : a32_1) : (bit0 ? a48_1 : paya1);
                    tt[2] = hi2 ? (bit0 ? paya0 : a48_0) : (bit0 ? a32_0 : a16_0);
                    tt[3] = hi2 ? (bit0 ? paya1 : a48_1) : (bit0 ? a32_1 : a16_1);
                    union { u32x4 u; bf16x8 b; } pa;
                    pa.u = tt;
#pragma unroll
                    for (int db = 0; db < 4; db++) {
                        int d = db * 16 + l15;
                        bf16x8 vb = *(const bf16x8*)&Vt[cur][d * 64 + (((kg * 4 + l4) ^ (d & 7)) << 3)];
                        o[db] = __builtin_amdgcn_mfma_f32_16x16x32_bf16(pa.b, vb, o[db], 0, 0, 0);
                    }
                }
                __builtin_amdgcn_s_setprio(0);
            }

            // ---- finish staging tile kt+1 ----
            if (havenext) {
                asm volatile("s_waitcnt vmcnt(0)" ::: "memory");
                u16 av[4], bv[4];
                *(u32x2*)av = va; *(u32x2*)bv = vb_;
#pragma unroll
                for (int j = 0; j < 4; j++) {
                    int d = vsd + j;
                    unsigned int word = (unsigned int)av[j] | ((unsigned int)bv[j] << 16);
                    int idx = d * 64 + ((((2 * vi) >> 3) ^ (d & 7)) << 3) + ((2 * vi) & 7);
                    *(unsigned int*)&Vt[cur ^ 1][idx] = word;
                }
            }
            __syncthreads();
            cur ^= 1;
        }

        // ---- epilogue: reduce l_ across the q-group, then write y ----
        l_ += __shfl_xor(l_, 16);
        l_ += __shfl_xor(l_, 32);
        float linv = 1.f / l_;
        float linv_o[4];
#pragma unroll
        for (int r = 0; r < 4; ++r)
            linv_o[r] = __shfl(linv, sgrp | (((lane >> 4) & 3) * 4 + r));
#pragma unroll
        for (int r = 0; r < 4; r++) {
            int qg = q0 + w * 16 + l4 * 4 + r;
            u16* yrow = y + (size_t)(b * Nn + qg) * Dd + h * DHd;
#pragma unroll
            for (int db = 0; db < 4; db++)
                yrow[db * 16 + l15] = f2bf(o[db][r] * linv_o[r]);
        }
    }
}

extern "C" void kernel_launch(void* const* d_in, const int* in_sizes, int n_in,
                              void* d_out, int out_size, void* d_ws, size_t ws_size,
                              hipStream_t stream) {
    const float* x = (const float*)d_in[0];
    const float* Wqkv = (const float*)d_in[1];
    const float* Wout = (const float*)d_in[2];

    char* ws = (char*)d_ws;
    size_t off = 0;
    u16* xb = (u16*)(ws + off);    off += (size_t)Mm * Dd * 2;     // 16 MiB
    u16* wqkvb = (u16*)(ws + off); off += (size_t)D3 * Dd * 2;     //  6 MiB
    u16* woutb = (u16*)(ws + off); off += (size_t)Dd * Dd * 2;     //  2 MiB
    u16* qkv = (u16*)(ws + off);   off += (size_t)Mm * D3 * 2;     // 48 MiB
    u16* yb = (u16*)(ws + off);    off += (size_t)Mm * Dd * 2;     // 16 MiB

    const float SCL = 0.125f * 1.4426950408889634f;  // (1/sqrt(DH)) * log2(e)

    cvt_f32_bf16<<<4096, 256, 0, stream>>>(x, xb, Mm * Dd / 4);
    cvt_f32_bf16_s<<<1024, 256, 0, stream>>>(Wqkv, wqkvb, D3 * Dd / 4, Dd * Dd / 4, SCL);
    cvt_f32_bf16<<<512, 256, 0, stream>>>(Wout, woutb, Dd * Dd / 4);

    gemm_bt<0><<<dim3(D3 / 128, Mm / 128), 256, 0, stream>>>(xb, wqkvb, qkv, Mm, D3, Dd);
    attn<<<dim3(Nn / 256, Bb * Hh), 512, 0, stream>>>(qkv, yb);
    gemm_bt<1><<<dim3(Dd / 128, Mm / 128), 256, 0, stream>>>(yb, woutb, d_out, Mm, Dd, Dd);
}